// Round 16
// baseline (193.165 us; speedup 1.0000x reference)
//
#include <hip/hip_runtime.h>
#include <hip/hip_bf16.h>

#define S_LEN 4096
#define NH    16
#define DD    128
#define HD    2048
#define QB    128
#define KB    64
#define NT    (S_LEN/KB)
#define NTH   (NT/2)      // 32 tiles per KV half

typedef __bf16 bf16_t;
typedef bf16_t bf16x8 __attribute__((ext_vector_type(8)));
typedef float  f32x4  __attribute__((ext_vector_type(4)));

static __device__ __forceinline__ bf16x8 pack8(float4 a, float4 b, float s) {
  bf16x8 v;
  v[0]=(bf16_t)(a.x*s); v[1]=(bf16_t)(a.y*s); v[2]=(bf16_t)(a.z*s); v[3]=(bf16_t)(a.w*s);
  v[4]=(bf16_t)(b.x*s); v[5]=(bf16_t)(b.y*s); v[6]=(bf16_t)(b.z*s); v[7]=(bf16_t)(b.w*s);
  return v;
}

static __device__ __forceinline__ void gload_lds16(const void* g, void* l) {
  __builtin_amdgcn_global_load_lds((const __attribute__((address_space(1))) void*)g,
                                   (__attribute__((address_space(3))) void*)l, 16, 0, 0);
}

// ---- prep K: fp32 [s][h][d] -> bf16 frag-major tiles [h][kt][f=(b,c)][lane][8] ----
__global__ __launch_bounds__(256) void prep_k(const float* __restrict__ Kg,
                                              bf16_t* __restrict__ Kp) {
  const int kt = blockIdx.x, h = blockIdx.y, tid = threadIdx.x;
  __shared__ bf16_t tile[KB][DD + 8];
  #pragma unroll
  for (int it = 0; it < 8; ++it) {
    int lin4 = it*256 + tid;
    int r  = lin4 >> 5;
    int dc = (lin4 & 31) * 4;
    float4 a = *(const float4*)(Kg + (size_t)(kt*KB + r)*HD + h*DD + dc);
    tile[r][dc+0]=(bf16_t)a.x; tile[r][dc+1]=(bf16_t)a.y;
    tile[r][dc+2]=(bf16_t)a.z; tile[r][dc+3]=(bf16_t)a.w;
  }
  __syncthreads();
  bf16_t* out = Kp + (size_t)(h*NT + kt)*8192;
  #pragma unroll
  for (int it = 0; it < 4; ++it) {
    int cid = it*256 + tid;
    int f = cid >> 6, l = cid & 63;
    int b = f >> 2, c = f & 3;
    int row = b*16 + (l & 15);
    int d0  = c*32 + (l >> 4)*8;
    bf16x8 v = *(const bf16x8*)(&tile[row][d0]);
    *(bf16x8*)(out + (size_t)cid*8) = v;
  }
}

// ---- prep V: fp32 [s][h][d] -> bf16 frag-major V^T tiles [h][kt][f=(ks,db)][lane][8] ----
__global__ __launch_bounds__(256) void prep_v(const float* __restrict__ Vg,
                                              bf16_t* __restrict__ Vp) {
  const int kt = blockIdx.x, h = blockIdx.y, tid = threadIdx.x;
  __shared__ bf16_t tile[KB][DD + 8];
  #pragma unroll
  for (int it = 0; it < 8; ++it) {
    int lin4 = it*256 + tid;
    int r  = lin4 >> 5;
    int dc = (lin4 & 31) * 4;
    float4 a = *(const float4*)(Vg + (size_t)(kt*KB + r)*HD + h*DD + dc);
    tile[r][dc+0]=(bf16_t)a.x; tile[r][dc+1]=(bf16_t)a.y;
    tile[r][dc+2]=(bf16_t)a.z; tile[r][dc+3]=(bf16_t)a.w;
  }
  __syncthreads();
  bf16_t* out = Vp + (size_t)(h*NT + kt)*8192;
  #pragma unroll
  for (int it = 0; it < 4; ++it) {
    int cid = it*256 + tid;
    int f = cid >> 6, l = cid & 63;
    int ks = f >> 3, db = f & 7;
    int d  = db*16 + (l & 15);
    int c0 = ks*32 + (l >> 4)*8;
    bf16x8 v;
    #pragma unroll
    for (int m = 0; m < 8; ++m) {
      int c = c0 + m;
      int k = 32*(c>>5) + 16*((c>>2)&1) + 4*((c>>3)&3) + (c&3);
      v[m] = tile[k][d];
    }
    *(bf16x8*)(out + (size_t)cid*8) = v;
  }
}

// ---- main: 4-wave blocks, half KV range each, 48KB LDS -> 3 blocks/CU ----
__global__ __launch_bounds__(256, 3) void attn_fwd(const float* __restrict__ Qg,
                                                   const bf16_t* __restrict__ Kp,
                                                   const bf16_t* __restrict__ Vp,
                                                   float* __restrict__ A0,   // = d_out, raw partial 0
                                                   float* __restrict__ A1,
                                                   float* __restrict__ lmW) {
  // chunked XCD swizzle: 1024 blocks, XCD x owns logical [x*128, x*128+128) = 2 heads
  const int phys = blockIdx.x;
  const int logical = (phys & 7) * 128 + (phys >> 3);
  const int h   = logical >> 6;
  const int rem = logical & 63;
  const int qt  = rem >> 1;          // q-tile of 128 rows
  const int p   = rem & 1;           // KV half
  const int tid  = threadIdx.x;
  const int wid  = tid >> 6;         // 0..3
  const int lane = tid & 63;
  const int l16  = lane & 15;
  const int lg   = lane >> 4;
  const int lo16 = lane * 16;
  const int kt0 = p * NTH;

  __shared__ alignas(16) bf16_t Ks[8192];      // 16KB, single-buffered K
  __shared__ alignas(16) bf16_t Vt[2][8192];   // 2x16KB, double-buffered V^T

  // ---- Q fragments for 2 q-groups (B-operand of swapped QK^T) ----
  const float qs = 0.08838834764831845f * 1.4426950408889634f;
  bf16x8 qf[2][4];
  #pragma unroll
  for (int g = 0; g < 2; ++g) {
    const int qrow = qt*QB + wid*32 + g*16 + l16;
    const float* qp = Qg + (size_t)qrow*HD + h*DD + lg*8;
    #pragma unroll
    for (int c = 0; c < 4; ++c) {
      float4 a = *(const float4*)(qp + c*32);
      float4 b = *(const float4*)(qp + c*32 + 4);
      qf[g][c] = pack8(a, b, qs);
    }
  }
  bf16x8 onesf;
  #pragma unroll
  for (int j = 0; j < 8; ++j) onesf[j] = (bf16_t)1.0f;
  asm volatile("" ::: "memory");

  // ---- staging: linear global->LDS DMA (4x16B per thread per operand tile) ----
  const int lo = tid*16;
  auto issueK = [&](int kt) {
    const char* kg = (const char*)(Kp + (size_t)(h*NT + kt)*8192);
    char* kl = (char*)&Ks[0];
    #pragma unroll
    for (int pp2 = 0; pp2 < 4; ++pp2) gload_lds16(kg + lo + pp2*4096, kl + lo + pp2*4096);
  };
  auto issueV = [&](int kt) {
    const char* vg = (const char*)(Vp + (size_t)(h*NT + kt)*8192);
    char* vl = (char*)&Vt[kt & 1][0];
    #pragma unroll
    for (int pp2 = 0; pp2 < 4; ++pp2) gload_lds16(vg + lo + pp2*4096, vl + lo + pp2*4096);
  };

  f32x4 acc[2][8];
  f32x4 acc_l[2];
  #pragma unroll
  for (int g = 0; g < 2; ++g) {
    #pragma unroll
    for (int i = 0; i < 8; ++i) acc[g][i] = (f32x4){0.f,0.f,0.f,0.f};
    acc_l[g] = (f32x4){0.f,0.f,0.f,0.f};
  }
  float m_run[2] = {-__builtin_inff(), -__builtin_inff()};

  issueK(kt0);
  issueV(kt0);

  for (int kt = kt0; kt < kt0 + NTH; ++kt) {
    const int cur = kt & 1;
    // ---- K(kt),V(kt) landed & all prior reads retired -> visible to all ----
    asm volatile("s_waitcnt vmcnt(0) lgkmcnt(0)" ::: "memory");
    __builtin_amdgcn_sched_barrier(0);
    __builtin_amdgcn_s_barrier();

    // V(kt+1) -> other buffer; lands any time before top of kt+1
    if (kt + 1 < kt0 + NTH) issueV(kt + 1);

    // ---- S^T = K Q^T : 32 MFMA; reads base + lane*16 + imm ----
    f32x4 sc[2][4];
    #pragma unroll
    for (int g = 0; g < 2; ++g)
      #pragma unroll
      for (int b = 0; b < 4; ++b) sc[g][b] = (f32x4){0.f,0.f,0.f,0.f};
    {
      const char* KsB = (const char*)&Ks[0] + lo16;
      __builtin_amdgcn_s_setprio(1);
      #pragma unroll
      for (int b = 0; b < 4; ++b) {
        #pragma unroll
        for (int c = 0; c < 4; ++c) {
          bf16x8 kb = *(const bf16x8*)(KsB + ((b*4 + c) << 10));
          sc[0][b] = __builtin_amdgcn_mfma_f32_16x16x32_bf16(kb, qf[0][c], sc[0][b], 0, 0, 0);
          sc[1][b] = __builtin_amdgcn_mfma_f32_16x16x32_bf16(kb, qf[1][c], sc[1][b], 0, 0, 0);
        }
      }
      __builtin_amdgcn_s_setprio(0);
    }

    // ---- all waves' QK reads retired -> safe to overwrite K buffer ----
    asm volatile("s_waitcnt lgkmcnt(0)" ::: "memory");
    __builtin_amdgcn_sched_barrier(0);
    __builtin_amdgcn_s_barrier();
    if (kt + 1 < kt0 + NTH) issueK(kt + 1);   // lands under softmax+PV

    // ---- online softmax, lane-local pmax fast path (defer-rescale THR=8) ----
    bf16x8 pp[2][2];
    #pragma unroll
    for (int g = 0; g < 2; ++g) {
      float pmax;
      {
        float a0 = fmaxf(fmaxf(sc[g][0][0], sc[g][0][1]), sc[g][0][2]);
        float a1 = fmaxf(fmaxf(sc[g][0][3], sc[g][1][0]), sc[g][1][1]);
        float a2 = fmaxf(fmaxf(sc[g][1][2], sc[g][1][3]), sc[g][2][0]);
        float a3 = fmaxf(fmaxf(sc[g][2][1], sc[g][2][2]), sc[g][2][3]);
        float a4 = fmaxf(fmaxf(sc[g][3][0], sc[g][3][1]), sc[g][3][2]);
        float b0 = fmaxf(fmaxf(a0, a1), a2);
        float b1 = fmaxf(fmaxf(a3, a4), sc[g][3][3]);
        pmax = fmaxf(b0, b1);   // LANE-LOCAL max of own 16 scores
      }
      if (!__all(pmax - m_run[g] <= 8.0f)) {
        // rare path: true row max via cross-lane, then rescale
        pmax = fmaxf(pmax, __shfl_xor(pmax, 16));
        pmax = fmaxf(pmax, __shfl_xor(pmax, 32));
        float mnew  = fmaxf(m_run[g], pmax);
        float alpha = exp2f(m_run[g] - mnew);    // first tile: exp2(-inf)=0
        m_run[g] = mnew;
        #pragma unroll
        for (int i = 0; i < 8; ++i) {
          #pragma unroll
          for (int r = 0; r < 4; ++r) acc[g][i][r] *= alpha;
        }
        #pragma unroll
        for (int r = 0; r < 4; ++r) acc_l[g][r] *= alpha;
      }
      #pragma unroll
      for (int b = 0; b < 4; ++b) {
        #pragma unroll
        for (int r = 0; r < 4; ++r) {
          float pv = exp2f(sc[g][b][r] - m_run[g]);   // bounded by 2^8
          pp[g][b >> 1][(b & 1)*4 + r] = (bf16_t)pv;
        }
      }
    }

    // ---- O^T += V^T P^T ; l += 1^T P^T : 36 MFMA, V read from LDS at use ----
    {
      const char* VtB = (const char*)&Vt[cur][0] + lo16;
      __builtin_amdgcn_s_setprio(1);
      #pragma unroll
      for (int ks = 0; ks < 2; ++ks) {
        acc_l[0] = __builtin_amdgcn_mfma_f32_16x16x32_bf16(onesf, pp[0][ks], acc_l[0], 0, 0, 0);
        acc_l[1] = __builtin_amdgcn_mfma_f32_16x16x32_bf16(onesf, pp[1][ks], acc_l[1], 0, 0, 0);
        #pragma unroll
        for (int db = 0; db < 8; ++db) {
          bf16x8 va = *(const bf16x8*)(VtB + ((ks*8 + db) << 10));
          acc[0][db] = __builtin_amdgcn_mfma_f32_16x16x32_bf16(va, pp[0][ks], acc[0][db], 0, 0, 0);
          acc[1][db] = __builtin_amdgcn_mfma_f32_16x16x32_bf16(va, pp[1][ks], acc[1][db], 0, 0, 0);
        }
      }
      __builtin_amdgcn_s_setprio(0);
    }
  }

  // ---- epilogue: store RAW partial acc + (l, m) per q-row ----
  float* Ap = p ? A1 : A0;
  #pragma unroll
  for (int g = 0; g < 2; ++g) {
    const int qrow = qt*QB + wid*32 + g*16 + l16;
    float* op = Ap + (size_t)qrow*HD + h*DD + lg*4;
    #pragma unroll
    for (int db = 0; db < 8; ++db) {
      float4 o;
      o.x = acc[g][db][0]; o.y = acc[g][db][1];
      o.z = acc[g][db][2]; o.w = acc[g][db][3];
      *(float4*)(op + db*16) = o;
    }
    if (lg == 0) {
      size_t row = (size_t)h*S_LEN + qrow;
      lmW[(size_t)p*131072 + row]         = acc_l[g][0];  // l
      lmW[(size_t)p*131072 + 65536 + row] = m_run[g];     // m (exp2 domain)
    }
  }
}

// ---- merge: O = (A0*2^(m0-m) + A1*2^(m1-m)) / (l0*2^(m0-m) + l1*2^(m1-m)) ----
__global__ __launch_bounds__(256) void merge2(const float* __restrict__ A1,
                                              const float* __restrict__ lmW,
                                              float* __restrict__ O) {
  size_t idx = (size_t)blockIdx.x*256 + threadIdx.x;   // one float4 of O
  size_t sh = idx >> 5;          // s*16 + h
  int hh = (int)(sh & 15);
  int ss = (int)(sh >> 4);
  size_t row = (size_t)hh*S_LEN + ss;
  float l0 = lmW[row],          m0 = lmW[65536 + row];
  float l1 = lmW[131072 + row], m1 = lmW[196608 + row];
  float m  = fmaxf(m0, m1);
  float w0 = exp2f(m0 - m), w1 = exp2f(m1 - m);
  float inv = 1.0f / (l0*w0 + l1*w1);
  float4 a0 = *(const float4*)(O  + idx*4);
  float4 a1 = *(const float4*)(A1 + idx*4);
  float4 o;
  o.x = (a0.x*w0 + a1.x*w1)*inv;
  o.y = (a0.y*w0 + a1.y*w1)*inv;
  o.z = (a0.z*w0 + a1.z*w1)*inv;
  o.w = (a0.w*w0 + a1.w*w1)*inv;
  *(float4*)(O + idx*4) = o;
}

extern "C" void kernel_launch(void* const* d_in, const int* in_sizes, int n_in,
                              void* d_out, int out_size, void* d_ws, size_t ws_size,
                              hipStream_t stream) {
  const float* Q = (const float*)d_in[0];
  const float* K = (const float*)d_in[1];
  const float* V = (const float*)d_in[2];
  float* O = (float*)d_out;
  bf16_t* Kp = (bf16_t*)d_ws;                   // 16.78 MB
  bf16_t* Vp = Kp + (size_t)8388608;            // 16.78 MB
  float*  A1 = (float*)(Vp + (size_t)8388608);  // 33.55 MB raw partial 1
  float*  lm = A1 + (size_t)8388608;            // 1.05 MB (4 planes of 65536)
  prep_k<<<dim3(NT, NH), 256, 0, stream>>>(K, Kp);
  prep_v<<<dim3(NT, NH), 256, 0, stream>>>(V, Vp);
  attn_fwd<<<dim3(1024), 256, 0, stream>>>(Q, Kp, Vp, O, A1, lm);
  merge2<<<dim3(8192), 256, 0, stream>>>(A1, lm, O);
}

// Round 17
// 184.163 us; speedup vs baseline: 1.0489x; 1.0489x over previous
//
#include <hip/hip_runtime.h>
#include <hip/hip_bf16.h>

#define S_LEN 4096
#define NH    16
#define DD    128
#define HD    2048
#define QB    128
#define KB    64
#define NT    (S_LEN/KB)
#define SPLIT 43          // long blocks: tiles [0,43); short: [43,64)

typedef __bf16 bf16_t;
typedef bf16_t bf16x8 __attribute__((ext_vector_type(8)));
typedef float  f32x4  __attribute__((ext_vector_type(4)));

static __device__ __forceinline__ bf16x8 pack8(float4 a, float4 b, float s) {
  bf16x8 v;
  v[0]=(bf16_t)(a.x*s); v[1]=(bf16_t)(a.y*s); v[2]=(bf16_t)(a.z*s); v[3]=(bf16_t)(a.w*s);
  v[4]=(bf16_t)(b.x*s); v[5]=(bf16_t)(b.y*s); v[6]=(bf16_t)(b.z*s); v[7]=(bf16_t)(b.w*s);
  return v;
}

static __device__ __forceinline__ void gload_lds16(const void* g, void* l) {
  __builtin_amdgcn_global_load_lds((const __attribute__((address_space(1))) void*)g,
                                   (__attribute__((address_space(3))) void*)l, 16, 0, 0);
}

// ---- prep K: fp32 [s][h][d] -> bf16 frag-major tiles [h][kt][f=(b,c)][lane][8] ----
__global__ __launch_bounds__(256) void prep_k(const float* __restrict__ Kg,
                                              bf16_t* __restrict__ Kp) {
  const int kt = blockIdx.x, h = blockIdx.y, tid = threadIdx.x;
  __shared__ bf16_t tile[KB][DD + 8];
  #pragma unroll
  for (int it = 0; it < 8; ++it) {
    int lin4 = it*256 + tid;
    int r  = lin4 >> 5;
    int dc = (lin4 & 31) * 4;
    float4 a = *(const float4*)(Kg + (size_t)(kt*KB + r)*HD + h*DD + dc);
    tile[r][dc+0]=(bf16_t)a.x; tile[r][dc+1]=(bf16_t)a.y;
    tile[r][dc+2]=(bf16_t)a.z; tile[r][dc+3]=(bf16_t)a.w;
  }
  __syncthreads();
  bf16_t* out = Kp + (size_t)(h*NT + kt)*8192;
  #pragma unroll
  for (int it = 0; it < 4; ++it) {
    int cid = it*256 + tid;
    int f = cid >> 6, l = cid & 63;
    int b = f >> 2, c = f & 3;
    int row = b*16 + (l & 15);
    int d0  = c*32 + (l >> 4)*8;
    bf16x8 v = *(const bf16x8*)(&tile[row][d0]);
    *(bf16x8*)(out + (size_t)cid*8) = v;
  }
}

// ---- prep V: fp32 [s][h][d] -> bf16 frag-major V^T tiles [h][kt][f=(ks,db)][lane][8] ----
__global__ __launch_bounds__(256) void prep_v(const float* __restrict__ Vg,
                                              bf16_t* __restrict__ Vp) {
  const int kt = blockIdx.x, h = blockIdx.y, tid = threadIdx.x;
  __shared__ bf16_t tile[KB][DD + 8];
  #pragma unroll
  for (int it = 0; it < 8; ++it) {
    int lin4 = it*256 + tid;
    int r  = lin4 >> 5;
    int dc = (lin4 & 31) * 4;
    float4 a = *(const float4*)(Vg + (size_t)(kt*KB + r)*HD + h*DD + dc);
    tile[r][dc+0]=(bf16_t)a.x; tile[r][dc+1]=(bf16_t)a.y;
    tile[r][dc+2]=(bf16_t)a.z; tile[r][dc+3]=(bf16_t)a.w;
  }
  __syncthreads();
  bf16_t* out = Vp + (size_t)(h*NT + kt)*8192;
  #pragma unroll
  for (int it = 0; it < 4; ++it) {
    int cid = it*256 + tid;
    int f = cid >> 6, l = cid & 63;
    int ks = f >> 3, db = f & 7;
    int d  = db*16 + (l & 15);
    int c0 = ks*32 + (l >> 4)*8;
    bf16x8 v;
    #pragma unroll
    for (int m = 0; m < 8; ++m) {
      int c = c0 + m;
      int k = 32*(c>>5) + 16*((c>>2)&1) + 4*((c>>3)&3) + (c&3);
      v[m] = tile[k][d];
    }
    *(bf16x8*)(out + (size_t)cid*8) = v;
  }
}

// ---- main: 4-wave blocks, uneven KV split (43/21), 48KB LDS -> 3 blocks/CU ----
__global__ __launch_bounds__(256, 3) void attn_fwd(const float* __restrict__ Qg,
                                                   const bf16_t* __restrict__ Kp,
                                                   const bf16_t* __restrict__ Vp,
                                                   float* __restrict__ A0,   // = d_out, raw partial 0
                                                   float* __restrict__ A1,
                                                   float* __restrict__ lmW) {
  // chunked XCD swizzle: 1024 blocks, XCD x owns logical [x*128, x*128+128) = 2 heads.
  // Within each head's 64 logicals: first 32 = LONG blocks (tiles [0,43)), next
  // 32 = SHORT (tiles [43,64)) -> longs dispatch first, shorts pack the tail.
  const int phys = blockIdx.x;
  const int logical = (phys & 7) * 128 + (phys >> 3);
  const int h   = logical >> 6;
  const int rem = logical & 63;
  const int p   = rem >> 5;          // 0 = long, 1 = short
  const int qt  = rem & 31;          // q-tile of 128 rows
  const int tid  = threadIdx.x;
  const int wid  = tid >> 6;         // 0..3
  const int lane = tid & 63;
  const int l16  = lane & 15;
  const int lg   = lane >> 4;
  const int lo16 = lane * 16;
  const int kt0   = p ? SPLIT : 0;
  const int ktEnd = p ? NT : SPLIT;

  __shared__ alignas(16) bf16_t Ks[8192];      // 16KB, single-buffered K
  __shared__ alignas(16) bf16_t Vt[2][8192];   // 2x16KB, double-buffered V^T

  // ---- Q fragments for 2 q-groups (B-operand of swapped QK^T) ----
  const float qs = 0.08838834764831845f * 1.4426950408889634f;
  bf16x8 qf[2][4];
  #pragma unroll
  for (int g = 0; g < 2; ++g) {
    const int qrow = qt*QB + wid*32 + g*16 + l16;
    const float* qp = Qg + (size_t)qrow*HD + h*DD + lg*8;
    #pragma unroll
    for (int c = 0; c < 4; ++c) {
      float4 a = *(const float4*)(qp + c*32);
      float4 b = *(const float4*)(qp + c*32 + 4);
      qf[g][c] = pack8(a, b, qs);
    }
  }
  bf16x8 onesf;
  #pragma unroll
  for (int j = 0; j < 8; ++j) onesf[j] = (bf16_t)1.0f;
  asm volatile("" ::: "memory");

  // ---- staging: linear global->LDS DMA (4x16B per thread per operand tile) ----
  const int lo = tid*16;
  auto issueK = [&](int kt) {
    const char* kg = (const char*)(Kp + (size_t)(h*NT + kt)*8192);
    char* kl = (char*)&Ks[0];
    #pragma unroll
    for (int pp2 = 0; pp2 < 4; ++pp2) gload_lds16(kg + lo + pp2*4096, kl + lo + pp2*4096);
  };
  auto issueV = [&](int kt) {
    const char* vg = (const char*)(Vp + (size_t)(h*NT + kt)*8192);
    char* vl = (char*)&Vt[kt & 1][0];
    #pragma unroll
    for (int pp2 = 0; pp2 < 4; ++pp2) gload_lds16(vg + lo + pp2*4096, vl + lo + pp2*4096);
  };

  f32x4 acc[2][8];
  f32x4 acc_l[2];
  #pragma unroll
  for (int g = 0; g < 2; ++g) {
    #pragma unroll
    for (int i = 0; i < 8; ++i) acc[g][i] = (f32x4){0.f,0.f,0.f,0.f};
    acc_l[g] = (f32x4){0.f,0.f,0.f,0.f};
  }
  float m_run[2] = {-__builtin_inff(), -__builtin_inff()};

  issueK(kt0);
  issueV(kt0);

  for (int kt = kt0; kt < ktEnd; ++kt) {
    const int cur = kt & 1;
    // ---- K(kt),V(kt) landed & all prior reads retired -> visible to all ----
    asm volatile("s_waitcnt vmcnt(0) lgkmcnt(0)" ::: "memory");
    __builtin_amdgcn_sched_barrier(0);
    __builtin_amdgcn_s_barrier();

    // V(kt+1) -> other buffer; lands any time before top of kt+1
    if (kt + 1 < ktEnd) issueV(kt + 1);

    // ---- S^T = K Q^T : 32 MFMA; reads base + lane*16 + imm ----
    f32x4 sc[2][4];
    #pragma unroll
    for (int g = 0; g < 2; ++g)
      #pragma unroll
      for (int b = 0; b < 4; ++b) sc[g][b] = (f32x4){0.f,0.f,0.f,0.f};
    {
      const char* KsB = (const char*)&Ks[0] + lo16;
      __builtin_amdgcn_s_setprio(1);
      #pragma unroll
      for (int b = 0; b < 4; ++b) {
        #pragma unroll
        for (int c = 0; c < 4; ++c) {
          bf16x8 kb = *(const bf16x8*)(KsB + ((b*4 + c) << 10));
          sc[0][b] = __builtin_amdgcn_mfma_f32_16x16x32_bf16(kb, qf[0][c], sc[0][b], 0, 0, 0);
          sc[1][b] = __builtin_amdgcn_mfma_f32_16x16x32_bf16(kb, qf[1][c], sc[1][b], 0, 0, 0);
        }
      }
      __builtin_amdgcn_s_setprio(0);
    }

    // ---- all waves' QK reads retired -> safe to overwrite K buffer ----
    asm volatile("s_waitcnt lgkmcnt(0)" ::: "memory");
    __builtin_amdgcn_sched_barrier(0);
    __builtin_amdgcn_s_barrier();
    if (kt + 1 < ktEnd) issueK(kt + 1);   // lands under softmax+PV

    // ---- online softmax, lane-local pmax fast path (defer-rescale THR=8) ----
    bf16x8 pp[2][2];
    #pragma unroll
    for (int g = 0; g < 2; ++g) {
      float pmax;
      {
        float a0 = fmaxf(fmaxf(sc[g][0][0], sc[g][0][1]), sc[g][0][2]);
        float a1 = fmaxf(fmaxf(sc[g][0][3], sc[g][1][0]), sc[g][1][1]);
        float a2 = fmaxf(fmaxf(sc[g][1][2], sc[g][1][3]), sc[g][2][0]);
        float a3 = fmaxf(fmaxf(sc[g][2][1], sc[g][2][2]), sc[g][2][3]);
        float a4 = fmaxf(fmaxf(sc[g][3][0], sc[g][3][1]), sc[g][3][2]);
        float b0 = fmaxf(fmaxf(a0, a1), a2);
        float b1 = fmaxf(fmaxf(a3, a4), sc[g][3][3]);
        pmax = fmaxf(b0, b1);   // LANE-LOCAL max of own 16 scores
      }
      if (!__all(pmax - m_run[g] <= 8.0f)) {
        // rare path: true row max via cross-lane, then rescale
        pmax = fmaxf(pmax, __shfl_xor(pmax, 16));
        pmax = fmaxf(pmax, __shfl_xor(pmax, 32));
        float mnew  = fmaxf(m_run[g], pmax);
        float alpha = exp2f(m_run[g] - mnew);    // first tile: exp2(-inf)=0
        m_run[g] = mnew;
        #pragma unroll
        for (int i = 0; i < 8; ++i) {
          #pragma unroll
          for (int r = 0; r < 4; ++r) acc[g][i][r] *= alpha;
        }
        #pragma unroll
        for (int r = 0; r < 4; ++r) acc_l[g][r] *= alpha;
      }
      #pragma unroll
      for (int b = 0; b < 4; ++b) {
        #pragma unroll
        for (int r = 0; r < 4; ++r) {
          float pv = exp2f(sc[g][b][r] - m_run[g]);   // bounded by 2^8
          pp[g][b >> 1][(b & 1)*4 + r] = (bf16_t)pv;
        }
      }
    }

    // ---- O^T += V^T P^T ; l += 1^T P^T : 36 MFMA, V read from LDS at use ----
    {
      const char* VtB = (const char*)&Vt[cur][0] + lo16;
      __builtin_amdgcn_s_setprio(1);
      #pragma unroll
      for (int ks = 0; ks < 2; ++ks) {
        acc_l[0] = __builtin_amdgcn_mfma_f32_16x16x32_bf16(onesf, pp[0][ks], acc_l[0], 0, 0, 0);
        acc_l[1] = __builtin_amdgcn_mfma_f32_16x16x32_bf16(onesf, pp[1][ks], acc_l[1], 0, 0, 0);
        #pragma unroll
        for (int db = 0; db < 8; ++db) {
          bf16x8 va = *(const bf16x8*)(VtB + ((ks*8 + db) << 10));
          acc[0][db] = __builtin_amdgcn_mfma_f32_16x16x32_bf16(va, pp[0][ks], acc[0][db], 0, 0, 0);
          acc[1][db] = __builtin_amdgcn_mfma_f32_16x16x32_bf16(va, pp[1][ks], acc[1][db], 0, 0, 0);
        }
      }
      __builtin_amdgcn_s_setprio(0);
    }
  }

  // ---- epilogue: store RAW partial acc + (l, m) per q-row ----
  float* Ap = p ? A1 : A0;
  #pragma unroll
  for (int g = 0; g < 2; ++g) {
    const int qrow = qt*QB + wid*32 + g*16 + l16;
    float* op = Ap + (size_t)qrow*HD + h*DD + lg*4;
    #pragma unroll
    for (int db = 0; db < 8; ++db) {
      float4 o;
      o.x = acc[g][db][0]; o.y = acc[g][db][1];
      o.z = acc[g][db][2]; o.w = acc[g][db][3];
      *(float4*)(op + db*16) = o;
    }
    if (lg == 0) {
      size_t row = (size_t)h*S_LEN + qrow;
      lmW[(size_t)p*131072 + row]         = acc_l[g][0];  // l
      lmW[(size_t)p*131072 + 65536 + row] = m_run[g];     // m (exp2 domain)
    }
  }
}

// ---- merge: O = (A0*2^(m0-m) + A1*2^(m1-m)) / (l0*2^(m0-m) + l1*2^(m1-m)) ----
__global__ __launch_bounds__(256) void merge2(const float* __restrict__ A1,
                                              const float* __restrict__ lmW,
                                              float* __restrict__ O) {
  size_t idx = (size_t)blockIdx.x*256 + threadIdx.x;   // one float4 of O
  size_t sh = idx >> 5;          // s*16 + h
  int hh = (int)(sh & 15);
  int ss = (int)(sh >> 4);
  size_t row = (size_t)hh*S_LEN + ss;
  float l0 = lmW[row],          m0 = lmW[65536 + row];
  float l1 = lmW[131072 + row], m1 = lmW[196608 + row];
  float m  = fmaxf(m0, m1);
  float w0 = exp2f(m0 - m), w1 = exp2f(m1 - m);
  float inv = 1.0f / (l0*w0 + l1*w1);
  float4 a0 = *(const float4*)(O  + idx*4);
  float4 a1 = *(const float4*)(A1 + idx*4);
  float4 o;
  o.x = (a0.x*w0 + a1.x*w1)*inv;
  o.y = (a0.y*w0 + a1.y*w1)*inv;
  o.z = (a0.z*w0 + a1.z*w1)*inv;
  o.w = (a0.w*w0 + a1.w*w1)*inv;
  *(float4*)(O + idx*4) = o;
}

extern "C" void kernel_launch(void* const* d_in, const int* in_sizes, int n_in,
                              void* d_out, int out_size, void* d_ws, size_t ws_size,
                              hipStream_t stream) {
  const float* Q = (const float*)d_in[0];
  const float* K = (const float*)d_in[1];
  const float* V = (const float*)d_in[2];
  float* O = (float*)d_out;
  bf16_t* Kp = (bf16_t*)d_ws;                   // 16.78 MB
  bf16_t* Vp = Kp + (size_t)8388608;            // 16.78 MB
  float*  A1 = (float*)(Vp + (size_t)8388608);  // 33.55 MB raw partial 1
  float*  lm = A1 + (size_t)8388608;            // 1.05 MB (4 planes of 65536)
  prep_k<<<dim3(NT, NH), 256, 0, stream>>>(K, Kp);
  prep_v<<<dim3(NT, NH), 256, 0, stream>>>(V, Vp);
  attn_fwd<<<dim3(1024), 256, 0, stream>>>(Q, Kp, Vp, O, A1, lm);
  merge2<<<dim3(8192), 256, 0, stream>>>(A1, lm, O);
}